// Round 13
// baseline (93.701 us; speedup 1.0000x reference)
//
#include <hip/hip_runtime.h>

#define NB 8192
#define OT_ELEMS (NB * 1024)   // floats of Ot, then Mt
#define EPSF 1e-10f

typedef __attribute__((ext_vector_type(4))) float f32x4;
typedef __attribute__((ext_vector_type(8))) short s16x8;   // 8 bf16 (4 VGPRs)

// Wave-local DS phase fence WITHOUT "memory" clobber (R9-R12 replay-proven).
#define SBAR() __builtin_amdgcn_sched_barrier(0)
#define LGK()  do { SBAR(); asm volatile("s_waitcnt lgkmcnt(0)"); SBAR(); } while (0)

#define MFMA_B16(A, B, C) __builtin_amdgcn_mfma_f32_16x16x32_bf16((A), (B), (C), 0, 0, 0)

// ---------------- Kernel 1: Cayley matrices M = (I-S)^-1 (I+S), stored ROW-major ----------------
__global__ void cayley_kernel(const float* __restrict__ Br,
                              const float* __restrict__ Bt,
                              const float* __restrict__ By,
                              float* __restrict__ M_out) {
  __shared__ float A[32][33];
  __shared__ float R[32][33];
  const float* B = (blockIdx.x == 0) ? Br : (blockIdx.x == 1) ? Bt : By;
  const int t = threadIdx.x;
  const int i = t >> 5, j = t & 31;
  float Lij = (j < i) ? B[i - 1 + j] : 0.0f;
  float Lji = (i < j) ? B[j - 1 + i] : 0.0f;
  float S = Lij - Lji;
  float eye = (i == j) ? 1.0f : 0.0f;
  A[i][j] = eye - S;   // I - S
  R[i][j] = eye + S;   // I + S
  __syncthreads();
  for (int p = 0; p < 32; ++p) {
    float f = A[i][p] / A[p][p];
    __syncthreads();
    if (i != p) {
      A[i][j] -= f * A[p][j];
      R[i][j] -= f * R[p][j];
    }
    __syncthreads();
  }
  // ROW-major: slot0=MR(0), slot1=MT(1024), slot2=MY(2048)
  M_out[blockIdx.x * 1024 + i * 32 + j] = R[i][j] / A[i][i];
}

// ---------------- Kernel 1b: P = MT*MR (fp32), ROW-major into ws slot 3 ----------------
__global__ void combine_kernel(float* __restrict__ ws) {
  __shared__ float sMR[1024], sMT[1024];
  const int t = threadIdx.x;
  sMR[t] = ws[t];
  sMT[t] = ws[1024 + t];
  __syncthreads();
  const int i = t >> 5, j = t & 31;
  float s = 0.f;
#pragma unroll
  for (int k = 0; k < 32; ++k)
    s = fmaf(sMT[i * 32 + k], sMR[k * 32 + j], s);
  ws[3072 + i * 32 + j] = s;   // P row-major
}

// fp32 -> bf16 hi/lo split (hi = truncated top 16 bits; lo = next 8+ mantissa bits)
__device__ __forceinline__ void cvt_hilo8(const f32x4 f0, const f32x4 f1, s16x8& hi, s16x8& lo) {
  float f[8];
#pragma unroll
  for (int e = 0; e < 4; ++e) { f[e] = f0[e]; f[4 + e] = f1[e]; }
#pragma unroll
  for (int e = 0; e < 8; ++e) {
    unsigned u = __float_as_uint(f[e]);
    hi[e] = (short)(u >> 16);
    float ah = __uint_as_float(u & 0xffff0000u);
    lo[e] = (short)(__float_as_uint(f[e] - ah) >> 16);
  }
}

__device__ __forceinline__ void read_frag_lds(const float* sb, int off, s16x8& hi, s16x8& lo) {
  f32x4 f0 = *(const f32x4*)(sb + off);
  f32x4 f1 = *(const f32x4*)(sb + off + 4);
  cvt_hilo8(f0, f1, hi, lo);
}

// ---------------- Kernel 2: 4 independent waves per 256-thread block, one batch each ----------------
// Per-wave pipeline = R11 (best): Stage A dual-chain (X·MT || U·P) -> Phit;
// St = V' + cP*Phit; EMA loads issued before Stage B, consumed mid-Stage-B;
// Stage B: Ot = MY St MY^T. No __syncthreads — all LDS is wave-private.
__global__ __launch_bounds__(256) void spdsru_main(
    const float* __restrict__ X, const float* __restrict__ state,
    const float* __restrict__ WR, const float* __restrict__ Wt,
    const float* __restrict__ Wphi, const float* __restrict__ Ws,
    const float* __restrict__ Mg, float* __restrict__ out) {
  __shared__ __align__(16) float sbuf0[4][1184];
  __shared__ __align__(16) float sbuf1[4][1184];
  const int wave = threadIdx.x >> 6;
  const int lane = threadIdx.x & 63;
  float* sb0 = sbuf0[wave];
  float* sb1 = sbuf1[wave];
  const int l15 = lane & 15, l4 = lane >> 4;
  const int i0 = (lane >> 3) << 2, j0 = (lane & 7) << 2;
  // XCD-contiguous swizzle at block level (2048 blocks), 4 batches per block
  const int bid = blockIdx.x;
  const int batch = ((bid & 7) * ((NB / 4) >> 3) + (bid >> 3)) * 4 + wave;

  // M fragments: q=0 -> MT (slot1), q=1 -> P (slot3), q=2 -> MY (slot2)
  s16x8 Mh[3][2], Ml[3][2];
  {
    const int srcoff[3] = {1024, 3072, 2048};
#pragma unroll
    for (int q = 0; q < 3; ++q)
#pragma unroll
      for (int s = 0; s < 2; ++s) {
        const float* p = Mg + srcoff[q] + (16 * s + l15) * 32 + 8 * l4;
        cvt_hilo8(*(const f32x4*)p, *(const f32x4*)(p + 4), Mh[q][s], Ml[q][s]);
      }
  }

  // uniform scalar weights
  const float alpha[5] = {0.01f, 0.25f, 0.5f, 0.9f, 0.99f};
  float wr[5], va[5];
  float cP = 0.f;
  {
    float sR = 0.f, sS = 0.f, wq[5];
#pragma unroll
    for (int a = 0; a < 5; ++a) { float v = WR[a]; wr[a] = v * v; sR += v * v; }
#pragma unroll
    for (int a = 0; a < 5; ++a) { float v = Ws[a]; wq[a] = v * v; sS += v * v; }
    const float invR = 1.0f / (sR + EPSF), invS = 1.0f / (sS + EPSF);
#pragma unroll
    for (int a = 0; a < 5; ++a) {
      wr[a] *= invR;
      float w = wq[a] * invS;
      va[a] = w * (1.0f - alpha[a]);
      cP += w * alpha[a];
    }
  }
  const float wt2 = Wt[0] * Wt[0], wp2 = Wphi[0] * Wphi[0];
  const float at = wt2 / (wt2 + wp2 + EPSF);
  const float omat = 1.0f - at;

  // loads: X (NT) + state pass 1 (rowtile); fold U (Yt) and V'
  const float* xp = X + (size_t)batch * 1024;
  f32x4 x[4];
#pragma unroll
  for (int r = 0; r < 4; ++r)
    x[r] = __builtin_nontemporal_load((const f32x4*)(xp + (i0 + r) * 32 + j0));

  const float* stp = state + (size_t)batch * 5120;
  f32x4 U[4], V[4];
#pragma unroll
  for (int r = 0; r < 4; ++r) { U[r] = f32x4{0.f, 0.f, 0.f, 0.f}; V[r] = U[r]; }
#pragma unroll
  for (int a = 0; a < 5; ++a)
#pragma unroll
    for (int r = 0; r < 4; ++r) {
      const f32x4 v = *(const f32x4*)(stp + a * 1024 + (i0 + r) * 32 + j0);
      U[r] += wr[a] * v;
      V[r] += va[a] * v;
    }

  // ---- Stage A: dual-chain congruence (X with MT) || (U with P) ----
#pragma unroll
  for (int c = 0; c < 4; ++c) {
    f32x4 cx = {x[0][c], x[1][c], x[2][c], x[3][c]};
    f32x4 cu = {U[0][c], U[1][c], U[2][c], U[3][c]};
    *(f32x4*)(sb0 + (j0 + c) * 36 + i0) = cx;   // X col-major
    *(f32x4*)(sb1 + (j0 + c) * 36 + i0) = cu;   // U col-major
  }
  LGK();
  s16x8 BXh[2], BXl[2], BUh[2], BUl[2];
#pragma unroll
  for (int s = 0; s < 2; ++s) {
    read_frag_lds(sb0, (16 * s + l15) * 36 + 8 * l4, BXh[s], BXl[s]);
    read_frag_lds(sb1, (16 * s + l15) * 36 + 8 * l4, BUh[s], BUl[s]);
  }
  LGK();
  f32x4 gX[2][2], gU[2][2];
#pragma unroll
  for (int ms = 0; ms < 2; ++ms)
#pragma unroll
    for (int ns = 0; ns < 2; ++ns) {
      f32x4 a0 = {0.f, 0.f, 0.f, 0.f};
      a0 = MFMA_B16(Ml[0][ms], BXh[ns], a0);
      a0 = MFMA_B16(Mh[0][ms], BXl[ns], a0);
      a0 = MFMA_B16(Mh[0][ms], BXh[ns], a0);
      gX[ms][ns] = a0;
      f32x4 a1 = {0.f, 0.f, 0.f, 0.f};
      a1 = MFMA_B16(Ml[1][ms], BUh[ns], a1);
      a1 = MFMA_B16(Mh[1][ms], BUl[ns], a1);
      a1 = MFMA_B16(Mh[1][ms], BUh[ns], a1);
      gU[ms][ns] = a1;
    }
#pragma unroll
  for (int ms = 0; ms < 2; ++ms)
#pragma unroll
    for (int ns = 0; ns < 2; ++ns)
#pragma unroll
      for (int r = 0; r < 4; ++r) {
        sb0[(16 * ms + 4 * l4 + r) * 36 + 16 * ns + l15] = gX[ms][ns][r];
        sb1[(16 * ms + 4 * l4 + r) * 36 + 16 * ns + l15] = gU[ms][ns][r];
      }
  LGK();
  s16x8 AXh[2], AXl[2], AUh[2], AUl[2];
#pragma unroll
  for (int s = 0; s < 2; ++s) {
    read_frag_lds(sb0, (16 * s + l15) * 36 + 8 * l4, AXh[s], AXl[s]);
    read_frag_lds(sb1, (16 * s + l15) * 36 + 8 * l4, AUh[s], AUl[s]);
  }
  LGK();
  f32x4 ph[2][2];   // Phit in C-layout
#pragma unroll
  for (int ms = 0; ms < 2; ++ms)
#pragma unroll
    for (int ns = 0; ns < 2; ++ns) {
      f32x4 a0 = {0.f, 0.f, 0.f, 0.f};
      a0 = MFMA_B16(AXl[ms], Mh[0][ns], a0);
      a0 = MFMA_B16(AXh[ms], Ml[0][ns], a0);
      a0 = MFMA_B16(AXh[ms], Mh[0][ns], a0);
      f32x4 a1 = {0.f, 0.f, 0.f, 0.f};
      a1 = MFMA_B16(AUl[ms], Mh[1][ns], a1);
      a1 = MFMA_B16(AUh[ms], Ml[1][ns], a1);
      a1 = MFMA_B16(AUh[ms], Mh[1][ns], a1);
      ph[ms][ns] = omat * a0 + at * a1;
    }

  // ---- Phit C-layout -> rowtile ----
#pragma unroll
  for (int ms = 0; ms < 2; ++ms)
#pragma unroll
    for (int ns = 0; ns < 2; ++ns)
#pragma unroll
      for (int r = 0; r < 4; ++r)
        sb0[(16 * ms + 4 * l4 + r) * 36 + 16 * ns + l15] = ph[ms][ns][r];
  LGK();
  f32x4 ph4[4];
#pragma unroll
  for (int r = 0; r < 4; ++r)
    ph4[r] = *(const f32x4*)(sb0 + (i0 + r) * 36 + j0);
  LGK();

  // St = V' + cP*Phit (rowtile); stage into sb0 col-major for stage B
  f32x4 st4[4];
#pragma unroll
  for (int r = 0; r < 4; ++r) st4[r] = V[r] + cP * ph4[r];
#pragma unroll
  for (int c = 0; c < 4; ++c) {
    f32x4 cs = {st4[0][c], st4[1][c], st4[2][c], st4[3][c]};
    *(f32x4*)(sb0 + (j0 + c) * 36 + i0) = cs;
  }
  // ---- EMA ISSUE: re-read state (L2-hot) into regs; consumed mid-stage-B ----
  f32x4 raw[20];
#pragma unroll
  for (int a = 0; a < 5; ++a)
#pragma unroll
    for (int r = 0; r < 4; ++r)
      raw[a * 4 + r] = *(const f32x4*)(stp + a * 1024 + (i0 + r) * 32 + j0);
  LGK();

  // ---- Stage B: Ot = MY St MY^T ----
  s16x8 BSh[2], BSl[2];
#pragma unroll
  for (int s = 0; s < 2; ++s)
    read_frag_lds(sb0, (16 * s + l15) * 36 + 8 * l4, BSh[s], BSl[s]);
  LGK();
  f32x4 gS[2][2];
#pragma unroll
  for (int ms = 0; ms < 2; ++ms)
#pragma unroll
    for (int ns = 0; ns < 2; ++ns) {
      f32x4 acc = {0.f, 0.f, 0.f, 0.f};
      acc = MFMA_B16(Ml[2][ms], BSh[ns], acc);
      acc = MFMA_B16(Mh[2][ms], BSl[ns], acc);
      acc = MFMA_B16(Mh[2][ms], BSh[ns], acc);
      gS[ms][ns] = acc;
    }
  // ---- EMA CONSUME: Mt[a] = (1-al)*raw + al*Phit, NT store (overlaps stage B) ----
  float* outMt = out + OT_ELEMS + (size_t)batch * 5120;
#pragma unroll
  for (int a = 0; a < 5; ++a) {
    const float al = alpha[a], om = 1.0f - al;
#pragma unroll
    for (int r = 0; r < 4; ++r) {
      f32x4 w = om * raw[a * 4 + r] + al * ph4[r];
      __builtin_nontemporal_store(w, (f32x4*)(outMt + a * 1024 + (i0 + r) * 32 + j0));
    }
  }
#pragma unroll
  for (int ms = 0; ms < 2; ++ms)
#pragma unroll
    for (int ns = 0; ns < 2; ++ns)
#pragma unroll
      for (int r = 0; r < 4; ++r)
        sb0[(16 * ms + 4 * l4 + r) * 36 + 16 * ns + l15] = gS[ms][ns][r];
  LGK();
  s16x8 ASh[2], ASl[2];
#pragma unroll
  for (int s = 0; s < 2; ++s)
    read_frag_lds(sb0, (16 * s + l15) * 36 + 8 * l4, ASh[s], ASl[s]);
  LGK();
  f32x4 o[2][2];
#pragma unroll
  for (int ms = 0; ms < 2; ++ms)
#pragma unroll
    for (int ns = 0; ns < 2; ++ns) {
      f32x4 acc = {0.f, 0.f, 0.f, 0.f};
      acc = MFMA_B16(ASl[ms], Mh[2][ns], acc);
      acc = MFMA_B16(ASh[ms], Ml[2][ns], acc);
      acc = MFMA_B16(ASh[ms], Mh[2][ns], acc);
      o[ms][ns] = acc;
    }
#pragma unroll
  for (int ms = 0; ms < 2; ++ms)
#pragma unroll
    for (int ns = 0; ns < 2; ++ns)
#pragma unroll
      for (int r = 0; r < 4; ++r)
        sb0[(16 * ms + 4 * l4 + r) * 36 + 16 * ns + l15] = o[ms][ns][r];
  LGK();
  float* outOt = out + (size_t)batch * 1024;
#pragma unroll
  for (int r = 0; r < 4; ++r) {
    f32x4 ov = *(const f32x4*)(sb0 + (i0 + r) * 36 + j0);
    __builtin_nontemporal_store(ov, (f32x4*)(outOt + (i0 + r) * 32 + j0));
  }
}

extern "C" void kernel_launch(void* const* d_in, const int* in_sizes, int n_in,
                              void* d_out, int out_size, void* d_ws, size_t ws_size,
                              hipStream_t stream) {
  const float* X     = (const float*)d_in[0];
  const float* state = (const float*)d_in[1];
  const float* WR    = (const float*)d_in[2];
  const float* Wt    = (const float*)d_in[3];
  const float* Wphi  = (const float*)d_in[4];
  const float* Ws    = (const float*)d_in[5];
  const float* Br    = (const float*)d_in[6];
  const float* Bt    = (const float*)d_in[7];
  const float* By    = (const float*)d_in[8];
  float* m_ws = (float*)d_ws;   // 4*1024 floats: MR, MT, MY, P (row-major)
  float* outp = (float*)d_out;

  cayley_kernel<<<3, 1024, 0, stream>>>(Br, Bt, By, m_ws);
  combine_kernel<<<1, 1024, 0, stream>>>(m_ws);
  spdsru_main<<<NB / 4, 256, 0, stream>>>(X, state, WR, Wt, Wphi, Ws, m_ws, outp);
}

// Round 14
// 92.248 us; speedup vs baseline: 1.0158x; 1.0158x over previous
//
#include <hip/hip_runtime.h>

#define NB 8192
#define OT_ELEMS (NB * 1024)   // floats of Ot, then Mt
#define EPSF 1e-10f

typedef __attribute__((ext_vector_type(4))) float f32x4;
typedef __attribute__((ext_vector_type(8))) short s16x8;   // 8 bf16 (4 VGPRs)

// Wave-local DS phase fence WITHOUT "memory" clobber (R9-R13 replay-proven).
#define SBAR() __builtin_amdgcn_sched_barrier(0)
#define LGK()  do { SBAR(); asm volatile("s_waitcnt lgkmcnt(0)"); SBAR(); } while (0)

#define MFMA_B16(A, B, C) __builtin_amdgcn_mfma_f32_16x16x32_bf16((A), (B), (C), 0, 0, 0)

// ---------------- Kernel 1: Cayley matrices M = (I-S)^-1 (I+S), stored ROW-major ----------------
__global__ void cayley_kernel(const float* __restrict__ Br,
                              const float* __restrict__ Bt,
                              const float* __restrict__ By,
                              float* __restrict__ M_out) {
  __shared__ float A[32][33];
  __shared__ float R[32][33];
  const float* B = (blockIdx.x == 0) ? Br : (blockIdx.x == 1) ? Bt : By;
  const int t = threadIdx.x;
  const int i = t >> 5, j = t & 31;
  float Lij = (j < i) ? B[i - 1 + j] : 0.0f;
  float Lji = (i < j) ? B[j - 1 + i] : 0.0f;
  float S = Lij - Lji;
  float eye = (i == j) ? 1.0f : 0.0f;
  A[i][j] = eye - S;   // I - S
  R[i][j] = eye + S;   // I + S
  __syncthreads();
  for (int p = 0; p < 32; ++p) {
    float f = A[i][p] / A[p][p];
    __syncthreads();
    if (i != p) {
      A[i][j] -= f * A[p][j];
      R[i][j] -= f * R[p][j];
    }
    __syncthreads();
  }
  // ROW-major: slot0=MR(0), slot1=MT(1024), slot2=MY(2048)
  M_out[blockIdx.x * 1024 + i * 32 + j] = R[i][j] / A[i][i];
}

// ---------------- Kernel 1b: P = MT*MR (fp32), ROW-major into ws slot 3 ----------------
__global__ void combine_kernel(float* __restrict__ ws) {
  __shared__ float sMR[1024], sMT[1024];
  const int t = threadIdx.x;
  sMR[t] = ws[t];
  sMT[t] = ws[1024 + t];
  __syncthreads();
  const int i = t >> 5, j = t & 31;
  float s = 0.f;
#pragma unroll
  for (int k = 0; k < 32; ++k)
    s = fmaf(sMT[i * 32 + k], sMR[k * 32 + j], s);
  ws[3072 + i * 32 + j] = s;   // P row-major
}

// fp32 -> bf16 hi/lo split (hi = truncated top 16 bits; lo = next 8+ mantissa bits)
__device__ __forceinline__ void cvt_hilo8(const f32x4 f0, const f32x4 f1, s16x8& hi, s16x8& lo) {
  float f[8];
#pragma unroll
  for (int e = 0; e < 4; ++e) { f[e] = f0[e]; f[4 + e] = f1[e]; }
#pragma unroll
  for (int e = 0; e < 8; ++e) {
    unsigned u = __float_as_uint(f[e]);
    hi[e] = (short)(u >> 16);
    float ah = __uint_as_float(u & 0xffff0000u);
    lo[e] = (short)(__float_as_uint(f[e] - ah) >> 16);
  }
}

__device__ __forceinline__ void read_frag_lds(const float* sb, int off, s16x8& hi, s16x8& lo) {
  f32x4 f0 = *(const f32x4*)(sb + off);
  f32x4 f1 = *(const f32x4*)(sb + off + 4);
  cvt_hilo8(f0, f1, hi, lo);
}

// ---------------- Kernel 2: one batch per wave; R11 pipeline with X-chain front-running ----------------
// Algebra (R11-proven): P = MT*MR. Phit = (1-at)*MT X MT^T + at*P U P^T.
// St = V' + cP*Phit. Ot = MY St MY^T. Mt[a] = (1-al)*m[a](L2 re-read) + al*Phit.
// NEW vs R11: X loads issued FIRST, X-chain phase 1 (stage X -> B-frag -> gX=MT*X)
// runs while the 20 state loads are in flight; U,V fold (vmcnt wait) lands after gX.
__global__ __launch_bounds__(64) void spdsru_main(
    const float* __restrict__ X, const float* __restrict__ state,
    const float* __restrict__ WR, const float* __restrict__ Wt,
    const float* __restrict__ Wphi, const float* __restrict__ Ws,
    const float* __restrict__ Mg, float* __restrict__ out) {
  __shared__ __align__(16) float sb0[1184];
  __shared__ __align__(16) float sb1[1184];
  const int lane = threadIdx.x;
  const int l15 = lane & 15, l4 = lane >> 4;
  const int i0 = (lane >> 3) << 2, j0 = (lane & 7) << 2;
  // XCD-contiguous swizzle (8192 blocks): xcd = bid&7 owns a contiguous 1024-batch range
  const int bid = blockIdx.x;
  const int batch = (bid & 7) * (NB >> 3) + (bid >> 3);

  // ---- issue X loads FIRST (4 loads), then the 20 state loads ----
  const float* xp = X + (size_t)batch * 1024;
  f32x4 x[4];
#pragma unroll
  for (int r = 0; r < 4; ++r)
    x[r] = __builtin_nontemporal_load((const f32x4*)(xp + (i0 + r) * 32 + j0));

  const float* stp = state + (size_t)batch * 5120;
  f32x4 raw[20];
#pragma unroll
  for (int a = 0; a < 5; ++a)
#pragma unroll
    for (int r = 0; r < 4; ++r)
      raw[a * 4 + r] = *(const f32x4*)(stp + a * 1024 + (i0 + r) * 32 + j0);

  // M fragments: q=0 -> MT (slot1), q=1 -> P (slot3), q=2 -> MY (slot2)
  s16x8 Mh[3][2], Ml[3][2];
  {
    const int srcoff[3] = {1024, 3072, 2048};
#pragma unroll
    for (int q = 0; q < 3; ++q)
#pragma unroll
      for (int s = 0; s < 2; ++s) {
        const float* p = Mg + srcoff[q] + (16 * s + l15) * 32 + 8 * l4;
        cvt_hilo8(*(const f32x4*)p, *(const f32x4*)(p + 4), Mh[q][s], Ml[q][s]);
      }
  }

  // uniform scalar weights
  const float alpha[5] = {0.01f, 0.25f, 0.5f, 0.9f, 0.99f};
  float wr[5], va[5];
  float cP = 0.f;
  {
    float sR = 0.f, sS = 0.f, wq[5];
#pragma unroll
    for (int a = 0; a < 5; ++a) { float v = WR[a]; wr[a] = v * v; sR += v * v; }
#pragma unroll
    for (int a = 0; a < 5; ++a) { float v = Ws[a]; wq[a] = v * v; sS += v * v; }
    const float invR = 1.0f / (sR + EPSF), invS = 1.0f / (sS + EPSF);
#pragma unroll
    for (int a = 0; a < 5; ++a) {
      wr[a] *= invR;
      float w = wq[a] * invS;
      va[a] = w * (1.0f - alpha[a]);
      cP += w * alpha[a];
    }
  }
  const float wt2 = Wt[0] * Wt[0], wp2 = Wphi[0] * Wphi[0];
  const float at = wt2 / (wt2 + wp2 + EPSF);
  const float omat = 1.0f - at;

  // ---- P0: stage X col-major (waits only on the 4 X loads; 20 state loads stay in flight) ----
#pragma unroll
  for (int c = 0; c < 4; ++c) {
    f32x4 cx = {x[0][c], x[1][c], x[2][c], x[3][c]};
    *(f32x4*)(sb0 + (j0 + c) * 36 + i0) = cx;
  }
  LGK();

  // ---- P1: B-frags of X ----
  s16x8 BXh[2], BXl[2];
#pragma unroll
  for (int s = 0; s < 2; ++s)
    read_frag_lds(sb0, (16 * s + l15) * 36 + 8 * l4, BXh[s], BXl[s]);
  LGK();

  // ---- P2: gX = MT*X (state-independent); then fold U,V (vmcnt wait lands here) + stage U ----
  f32x4 gX[2][2];
#pragma unroll
  for (int ms = 0; ms < 2; ++ms)
#pragma unroll
    for (int ns = 0; ns < 2; ++ns) {
      f32x4 a0 = {0.f, 0.f, 0.f, 0.f};
      a0 = MFMA_B16(Ml[0][ms], BXh[ns], a0);
      a0 = MFMA_B16(Mh[0][ms], BXl[ns], a0);
      a0 = MFMA_B16(Mh[0][ms], BXh[ns], a0);
      gX[ms][ns] = a0;
    }
#pragma unroll
  for (int ms = 0; ms < 2; ++ms)
#pragma unroll
    for (int ns = 0; ns < 2; ++ns)
#pragma unroll
      for (int r = 0; r < 4; ++r)
        sb0[(16 * ms + 4 * l4 + r) * 36 + 16 * ns + l15] = gX[ms][ns][r];
  // fold U, V' from raw (releases raw)
  f32x4 U[4], V[4];
#pragma unroll
  for (int r = 0; r < 4; ++r) {
    f32x4 u = wr[0] * raw[r], v = va[0] * raw[r];
#pragma unroll
    for (int a = 1; a < 5; ++a) { u += wr[a] * raw[a * 4 + r]; v += va[a] * raw[a * 4 + r]; }
    U[r] = u; V[r] = v;
  }
#pragma unroll
  for (int c = 0; c < 4; ++c) {
    f32x4 cu = {U[0][c], U[1][c], U[2][c], U[3][c]};
    *(f32x4*)(sb1 + (j0 + c) * 36 + i0) = cu;
  }
  LGK();

  // ---- P3: A-frags of gX + B-frags of U ----
  s16x8 AXh[2], AXl[2], BUh[2], BUl[2];
#pragma unroll
  for (int s = 0; s < 2; ++s) {
    read_frag_lds(sb0, (16 * s + l15) * 36 + 8 * l4, AXh[s], AXl[s]);
    read_frag_lds(sb1, (16 * s + l15) * 36 + 8 * l4, BUh[s], BUl[s]);
  }
  LGK();

  // ---- P4: a0 = gX*MT^T ; gU = P*U -> stage gU ----
  f32x4 a0c[2][2], gU[2][2];
#pragma unroll
  for (int ms = 0; ms < 2; ++ms)
#pragma unroll
    for (int ns = 0; ns < 2; ++ns) {
      f32x4 a0 = {0.f, 0.f, 0.f, 0.f};
      a0 = MFMA_B16(AXl[ms], Mh[0][ns], a0);
      a0 = MFMA_B16(AXh[ms], Ml[0][ns], a0);
      a0 = MFMA_B16(AXh[ms], Mh[0][ns], a0);
      a0c[ms][ns] = a0;
      f32x4 a1 = {0.f, 0.f, 0.f, 0.f};
      a1 = MFMA_B16(Ml[1][ms], BUh[ns], a1);
      a1 = MFMA_B16(Mh[1][ms], BUl[ns], a1);
      a1 = MFMA_B16(Mh[1][ms], BUh[ns], a1);
      gU[ms][ns] = a1;
    }
#pragma unroll
  for (int ms = 0; ms < 2; ++ms)
#pragma unroll
    for (int ns = 0; ns < 2; ++ns)
#pragma unroll
      for (int r = 0; r < 4; ++r)
        sb1[(16 * ms + 4 * l4 + r) * 36 + 16 * ns + l15] = gU[ms][ns][r];
  LGK();

  // ---- P5: A-frags of gU ----
  s16x8 AUh[2], AUl[2];
#pragma unroll
  for (int s = 0; s < 2; ++s)
    read_frag_lds(sb1, (16 * s + l15) * 36 + 8 * l4, AUh[s], AUl[s]);
  LGK();

  // ---- P6: Phit = omat*a0 + at*(gU*P^T) ; stage ph row-major ----
  f32x4 ph[2][2];
#pragma unroll
  for (int ms = 0; ms < 2; ++ms)
#pragma unroll
    for (int ns = 0; ns < 2; ++ns) {
      f32x4 a1 = {0.f, 0.f, 0.f, 0.f};
      a1 = MFMA_B16(AUl[ms], Mh[1][ns], a1);
      a1 = MFMA_B16(AUh[ms], Ml[1][ns], a1);
      a1 = MFMA_B16(AUh[ms], Mh[1][ns], a1);
      ph[ms][ns] = omat * a0c[ms][ns] + at * a1;
    }
#pragma unroll
  for (int ms = 0; ms < 2; ++ms)
#pragma unroll
    for (int ns = 0; ns < 2; ++ns)
#pragma unroll
      for (int r = 0; r < 4; ++r)
        sb0[(16 * ms + 4 * l4 + r) * 36 + 16 * ns + l15] = ph[ms][ns][r];
  LGK();

  // ---- P7: ph rowtile read ----
  f32x4 ph4[4];
#pragma unroll
  for (int r = 0; r < 4; ++r)
    ph4[r] = *(const f32x4*)(sb0 + (i0 + r) * 36 + j0);
  LGK();

  // ---- P8: St = V' + cP*Phit -> stage col-major ; EMA ISSUE (L2-hot re-read) ----
  f32x4 st4[4];
#pragma unroll
  for (int r = 0; r < 4; ++r) st4[r] = V[r] + cP * ph4[r];
#pragma unroll
  for (int c = 0; c < 4; ++c) {
    f32x4 cs = {st4[0][c], st4[1][c], st4[2][c], st4[3][c]};
    *(f32x4*)(sb0 + (j0 + c) * 36 + i0) = cs;
  }
  f32x4 raw2[20];
#pragma unroll
  for (int a = 0; a < 5; ++a)
#pragma unroll
    for (int r = 0; r < 4; ++r)
      raw2[a * 4 + r] = *(const f32x4*)(stp + a * 1024 + (i0 + r) * 32 + j0);
  LGK();

  // ---- P9: B-frags of St ----
  s16x8 BSh[2], BSl[2];
#pragma unroll
  for (int s = 0; s < 2; ++s)
    read_frag_lds(sb0, (16 * s + l15) * 36 + 8 * l4, BSh[s], BSl[s]);
  LGK();

  // ---- P10: gS = MY*St ; EMA CONSUME (Mt NT stores overlap) ; stage gS ----
  f32x4 gS[2][2];
#pragma unroll
  for (int ms = 0; ms < 2; ++ms)
#pragma unroll
    for (int ns = 0; ns < 2; ++ns) {
      f32x4 acc = {0.f, 0.f, 0.f, 0.f};
      acc = MFMA_B16(Ml[2][ms], BSh[ns], acc);
      acc = MFMA_B16(Mh[2][ms], BSl[ns], acc);
      acc = MFMA_B16(Mh[2][ms], BSh[ns], acc);
      gS[ms][ns] = acc;
    }
  float* outMt = out + OT_ELEMS + (size_t)batch * 5120;
#pragma unroll
  for (int a = 0; a < 5; ++a) {
    const float al = alpha[a], om = 1.0f - al;
#pragma unroll
    for (int r = 0; r < 4; ++r) {
      f32x4 w = om * raw2[a * 4 + r] + al * ph4[r];
      __builtin_nontemporal_store(w, (f32x4*)(outMt + a * 1024 + (i0 + r) * 32 + j0));
    }
  }
#pragma unroll
  for (int ms = 0; ms < 2; ++ms)
#pragma unroll
    for (int ns = 0; ns < 2; ++ns)
#pragma unroll
      for (int r = 0; r < 4; ++r)
        sb0[(16 * ms + 4 * l4 + r) * 36 + 16 * ns + l15] = gS[ms][ns][r];
  LGK();

  // ---- P11: A-frags of gS ----
  s16x8 ASh[2], ASl[2];
#pragma unroll
  for (int s = 0; s < 2; ++s)
    read_frag_lds(sb0, (16 * s + l15) * 36 + 8 * l4, ASh[s], ASl[s]);
  LGK();

  // ---- P12: Ot = gS*MY^T ; stage row-major ----
  f32x4 o[2][2];
#pragma unroll
  for (int ms = 0; ms < 2; ++ms)
#pragma unroll
    for (int ns = 0; ns < 2; ++ns) {
      f32x4 acc = {0.f, 0.f, 0.f, 0.f};
      acc = MFMA_B16(ASl[ms], Mh[2][ns], acc);
      acc = MFMA_B16(ASh[ms], Ml[2][ns], acc);
      acc = MFMA_B16(ASh[ms], Mh[2][ns], acc);
      o[ms][ns] = acc;
    }
#pragma unroll
  for (int ms = 0; ms < 2; ++ms)
#pragma unroll
    for (int ns = 0; ns < 2; ++ns)
#pragma unroll
      for (int r = 0; r < 4; ++r)
        sb0[(16 * ms + 4 * l4 + r) * 36 + 16 * ns + l15] = o[ms][ns][r];
  LGK();

  // ---- P13: Ot rowtile read + NT store ----
  float* outOt = out + (size_t)batch * 1024;
#pragma unroll
  for (int r = 0; r < 4; ++r) {
    f32x4 ov = *(const f32x4*)(sb0 + (i0 + r) * 36 + j0);
    __builtin_nontemporal_store(ov, (f32x4*)(outOt + (i0 + r) * 32 + j0));
  }
}

extern "C" void kernel_launch(void* const* d_in, const int* in_sizes, int n_in,
                              void* d_out, int out_size, void* d_ws, size_t ws_size,
                              hipStream_t stream) {
  const float* X     = (const float*)d_in[0];
  const float* state = (const float*)d_in[1];
  const float* WR    = (const float*)d_in[2];
  const float* Wt    = (const float*)d_in[3];
  const float* Wphi  = (const float*)d_in[4];
  const float* Ws    = (const float*)d_in[5];
  const float* Br    = (const float*)d_in[6];
  const float* Bt    = (const float*)d_in[7];
  const float* By    = (const float*)d_in[8];
  float* m_ws = (float*)d_ws;   // 4*1024 floats: MR, MT, MY, P (row-major)
  float* outp = (float*)d_out;

  cayley_kernel<<<3, 1024, 0, stream>>>(Br, Bt, By, m_ws);
  combine_kernel<<<1, 1024, 0, stream>>>(m_ws);
  spdsru_main<<<NB, 64, 0, stream>>>(X, state, WR, Wt, Wphi, Ws, m_ws, outp);
}

// Round 16
// 89.180 us; speedup vs baseline: 1.0507x; 1.0344x over previous
//
#include <hip/hip_runtime.h>

#define NB 8192
#define OT_ELEMS (NB * 1024)   // floats of Ot, then Mt
#define EPSF 1e-10f

typedef __attribute__((ext_vector_type(4))) float f32x4;
typedef __attribute__((ext_vector_type(8))) short s16x8;   // 8 bf16 (4 VGPRs)

// Wave-local DS phase fence WITHOUT "memory" clobber (R9-R14 replay-proven).
// Guards exactly one cross-lane LDS RAW per use (write -> fence -> read).
#define SBAR() __builtin_amdgcn_sched_barrier(0)
#define LGK()  do { SBAR(); asm volatile("s_waitcnt lgkmcnt(0)"); SBAR(); } while (0)

#define MFMA_B16(A, B, C) __builtin_amdgcn_mfma_f32_16x16x32_bf16((A), (B), (C), 0, 0, 0)

// ---------------- Kernel 1: Cayley matrices M = (I-S)^-1 (I+S), stored ROW-major ----------------
__global__ void cayley_kernel(const float* __restrict__ Br,
                              const float* __restrict__ Bt,
                              const float* __restrict__ By,
                              float* __restrict__ M_out) {
  __shared__ float A[32][33];
  __shared__ float R[32][33];
  const float* B = (blockIdx.x == 0) ? Br : (blockIdx.x == 1) ? Bt : By;
  const int t = threadIdx.x;
  const int i = t >> 5, j = t & 31;
  float Lij = (j < i) ? B[i - 1 + j] : 0.0f;
  float Lji = (i < j) ? B[j - 1 + i] : 0.0f;
  float S = Lij - Lji;
  float eye = (i == j) ? 1.0f : 0.0f;
  A[i][j] = eye - S;   // I - S
  R[i][j] = eye + S;   // I + S
  __syncthreads();
  for (int p = 0; p < 32; ++p) {
    float f = A[i][p] / A[p][p];
    __syncthreads();
    if (i != p) {
      A[i][j] -= f * A[p][j];
      R[i][j] -= f * R[p][j];
    }
    __syncthreads();
  }
  // ROW-major: slot0=MR(0), slot1=MT(1024), slot2=MY(2048)
  M_out[blockIdx.x * 1024 + i * 32 + j] = R[i][j] / A[i][i];
}

// ---------------- Kernel 1b: P = MT*MR (fp32), ROW-major into ws slot 3 ----------------
__global__ void combine_kernel(float* __restrict__ ws) {
  __shared__ float sMR[1024], sMT[1024];
  const int t = threadIdx.x;
  sMR[t] = ws[t];
  sMT[t] = ws[1024 + t];
  __syncthreads();
  const int i = t >> 5, j = t & 31;
  float s = 0.f;
#pragma unroll
  for (int k = 0; k < 32; ++k)
    s = fmaf(sMT[i * 32 + k], sMR[k * 32 + j], s);
  ws[3072 + i * 32 + j] = s;   // P row-major
}

// fp32 -> bf16 hi/lo split (hi = truncated top 16 bits; lo = next 8+ mantissa bits)
__device__ __forceinline__ void cvt_hilo8(const f32x4 f0, const f32x4 f1, s16x8& hi, s16x8& lo) {
  float f[8];
#pragma unroll
  for (int e = 0; e < 4; ++e) { f[e] = f0[e]; f[4 + e] = f1[e]; }
#pragma unroll
  for (int e = 0; e < 8; ++e) {
    unsigned u = __float_as_uint(f[e]);
    hi[e] = (short)(u >> 16);
    float ah = __uint_as_float(u & 0xffff0000u);
    lo[e] = (short)(__float_as_uint(f[e] - ah) >> 16);
  }
}

__device__ __forceinline__ void read_frag_lds(const float* sb, int off, s16x8& hi, s16x8& lo) {
  f32x4 f0 = *(const f32x4*)(sb + off);
  f32x4 f1 = *(const f32x4*)(sb + off + 4);
  cvt_hilo8(f0, f1, hi, lo);
}

// ---------------- Kernel 2: one batch per wave; R11 algebra, 4-buffer ping-pong, 6 fences ----------------
// Algebra (R11-proven): P = MT*MR. Phit = (1-at)*MT X MT^T + at*P U P^T.
// St = V' + cP*Phit. Ot = MY St MY^T. Mt[a] = (1-al)*m[a](L2 re-read) + al*Phit.
// NEW vs R11: each staging write targets a buffer DIFFERENT from the phase's reads,
// so the 5 WAR-motivated fences (incl. all "after frag-read" drains) are removed.
// Hazard map (w=write, r=read):  1:w sb0,sb1 |F1| 2:r sb0,sb1 w sb2,sb3 |F2|
// 3:r sb2,sb3 w sb0 |F3| 4:r sb0 w sb1 |F4| 5:r sb1 w sb2 |F5| 6:r sb2 w sb3 |F6| 7:r sb3
__global__ __launch_bounds__(64) void spdsru_main(
    const float* __restrict__ X, const float* __restrict__ state,
    const float* __restrict__ WR, const float* __restrict__ Wt,
    const float* __restrict__ Wphi, const float* __restrict__ Ws,
    const float* __restrict__ Mg, float* __restrict__ out) {
  __shared__ __align__(16) float sb0[1152];
  __shared__ __align__(16) float sb1[1152];
  __shared__ __align__(16) float sb2[1152];
  __shared__ __align__(16) float sb3[1152];
  const int lane = threadIdx.x;
  const int l15 = lane & 15, l4 = lane >> 4;
  const int i0 = (lane >> 3) << 2, j0 = (lane & 7) << 2;
  // XCD-contiguous swizzle (8192 blocks): xcd = bid&7 owns a contiguous 1024-batch range
  const int bid = blockIdx.x;
  const int batch = (bid & 7) * (NB >> 3) + (bid >> 3);

  // M fragments: q=0 -> MT (slot1), q=1 -> P (slot3), q=2 -> MY (slot2)
  s16x8 Mh[3][2], Ml[3][2];
  {
    const int srcoff[3] = {1024, 3072, 2048};
#pragma unroll
    for (int q = 0; q < 3; ++q)
#pragma unroll
      for (int s = 0; s < 2; ++s) {
        const float* p = Mg + srcoff[q] + (16 * s + l15) * 32 + 8 * l4;
        cvt_hilo8(*(const f32x4*)p, *(const f32x4*)(p + 4), Mh[q][s], Ml[q][s]);
      }
  }

  // uniform scalar weights
  const float alpha[5] = {0.01f, 0.25f, 0.5f, 0.9f, 0.99f};
  float wr[5], va[5];
  float cP = 0.f;
  {
    float sR = 0.f, sS = 0.f, wq[5];
#pragma unroll
    for (int a = 0; a < 5; ++a) { float v = WR[a]; wr[a] = v * v; sR += v * v; }
#pragma unroll
    for (int a = 0; a < 5; ++a) { float v = Ws[a]; wq[a] = v * v; sS += v * v; }
    const float invR = 1.0f / (sR + EPSF), invS = 1.0f / (sS + EPSF);
#pragma unroll
    for (int a = 0; a < 5; ++a) {
      wr[a] *= invR;
      float w = wq[a] * invS;
      va[a] = w * (1.0f - alpha[a]);
      cP += w * alpha[a];
    }
  }
  const float wt2 = Wt[0] * Wt[0], wp2 = Wphi[0] * Wphi[0];
  const float at = wt2 / (wt2 + wp2 + EPSF);
  const float omat = 1.0f - at;

  // loads: X (NT) + state pass 1 (rowtile); fold U (Yt) and V' (raw not kept)
  const float* xp = X + (size_t)batch * 1024;
  f32x4 x[4];
#pragma unroll
  for (int r = 0; r < 4; ++r)
    x[r] = __builtin_nontemporal_load((const f32x4*)(xp + (i0 + r) * 32 + j0));

  const float* stp = state + (size_t)batch * 5120;
  f32x4 U[4], V[4];
#pragma unroll
  for (int r = 0; r < 4; ++r) { U[r] = f32x4{0.f, 0.f, 0.f, 0.f}; V[r] = U[r]; }
#pragma unroll
  for (int a = 0; a < 5; ++a)
#pragma unroll
    for (int r = 0; r < 4; ++r) {
      const f32x4 v = *(const f32x4*)(stp + a * 1024 + (i0 + r) * 32 + j0);
      U[r] += wr[a] * v;
      V[r] += va[a] * v;
    }

  // ---- Phase 1: stage X -> sb0, U -> sb1 (col-major, stride 36) ----
#pragma unroll
  for (int c = 0; c < 4; ++c) {
    f32x4 cx = {x[0][c], x[1][c], x[2][c], x[3][c]};
    f32x4 cu = {U[0][c], U[1][c], U[2][c], U[3][c]};
    *(f32x4*)(sb0 + (j0 + c) * 36 + i0) = cx;
    *(f32x4*)(sb1 + (j0 + c) * 36 + i0) = cu;
  }
  LGK();   // F1: RAW for BX/BU reads

  // ---- Phase 2: read BX<-sb0, BU<-sb1; gX=MT*X, gU=P*U; write gX->sb2, gU->sb3 ----
  s16x8 BXh[2], BXl[2], BUh[2], BUl[2];
#pragma unroll
  for (int s = 0; s < 2; ++s) {
    read_frag_lds(sb0, (16 * s + l15) * 36 + 8 * l4, BXh[s], BXl[s]);
    read_frag_lds(sb1, (16 * s + l15) * 36 + 8 * l4, BUh[s], BUl[s]);
  }
  {
    f32x4 gX[2][2], gU[2][2];
#pragma unroll
    for (int ms = 0; ms < 2; ++ms)
#pragma unroll
      for (int ns = 0; ns < 2; ++ns) {
        f32x4 a0 = {0.f, 0.f, 0.f, 0.f};
        a0 = MFMA_B16(Ml[0][ms], BXh[ns], a0);
        a0 = MFMA_B16(Mh[0][ms], BXl[ns], a0);
        a0 = MFMA_B16(Mh[0][ms], BXh[ns], a0);
        gX[ms][ns] = a0;
        f32x4 a1 = {0.f, 0.f, 0.f, 0.f};
        a1 = MFMA_B16(Ml[1][ms], BUh[ns], a1);
        a1 = MFMA_B16(Mh[1][ms], BUl[ns], a1);
        a1 = MFMA_B16(Mh[1][ms], BUh[ns], a1);
        gU[ms][ns] = a1;
      }
#pragma unroll
    for (int ms = 0; ms < 2; ++ms)
#pragma unroll
      for (int ns = 0; ns < 2; ++ns)
#pragma unroll
        for (int r = 0; r < 4; ++r) {
          sb2[(16 * ms + 4 * l4 + r) * 36 + 16 * ns + l15] = gX[ms][ns][r];
          sb3[(16 * ms + 4 * l4 + r) * 36 + 16 * ns + l15] = gU[ms][ns][r];
        }
  }
  LGK();   // F2: RAW for AX/AU reads

  // ---- Phase 3: read AX<-sb2, AU<-sb3; Phit = omat*(gX*MT^T) + at*(gU*P^T); write ph->sb0 ----
  {
    s16x8 AXh[2], AXl[2], AUh[2], AUl[2];
#pragma unroll
    for (int s = 0; s < 2; ++s) {
      read_frag_lds(sb2, (16 * s + l15) * 36 + 8 * l4, AXh[s], AXl[s]);
      read_frag_lds(sb3, (16 * s + l15) * 36 + 8 * l4, AUh[s], AUl[s]);
    }
    f32x4 ph[2][2];
#pragma unroll
    for (int ms = 0; ms < 2; ++ms)
#pragma unroll
      for (int ns = 0; ns < 2; ++ns) {
        f32x4 a0 = {0.f, 0.f, 0.f, 0.f};
        a0 = MFMA_B16(AXl[ms], Mh[0][ns], a0);
        a0 = MFMA_B16(AXh[ms], Ml[0][ns], a0);
        a0 = MFMA_B16(AXh[ms], Mh[0][ns], a0);
        f32x4 a1 = {0.f, 0.f, 0.f, 0.f};
        a1 = MFMA_B16(AUl[ms], Mh[1][ns], a1);
        a1 = MFMA_B16(AUh[ms], Ml[1][ns], a1);
        a1 = MFMA_B16(AUh[ms], Mh[1][ns], a1);
        ph[ms][ns] = omat * a0 + at * a1;
      }
#pragma unroll
    for (int ms = 0; ms < 2; ++ms)
#pragma unroll
      for (int ns = 0; ns < 2; ++ns)
#pragma unroll
        for (int r = 0; r < 4; ++r)
          sb0[(16 * ms + 4 * l4 + r) * 36 + 16 * ns + l15] = ph[ms][ns][r];
  }
  LGK();   // F3: RAW for ph4 rowtile read

  // ---- Phase 4: read ph4<-sb0 (rowtile); St = V' + cP*Phit; write St->sb1; issue EMA re-read ----
  f32x4 ph4[4];
#pragma unroll
  for (int r = 0; r < 4; ++r)
    ph4[r] = *(const f32x4*)(sb0 + (i0 + r) * 36 + j0);
  f32x4 st4[4];
#pragma unroll
  for (int r = 0; r < 4; ++r) st4[r] = V[r] + cP * ph4[r];
#pragma unroll
  for (int c = 0; c < 4; ++c) {
    f32x4 cs = {st4[0][c], st4[1][c], st4[2][c], st4[3][c]};
    *(f32x4*)(sb1 + (j0 + c) * 36 + i0) = cs;
  }
  f32x4 raw2[20];
#pragma unroll
  for (int a = 0; a < 5; ++a)
#pragma unroll
    for (int r = 0; r < 4; ++r)
      raw2[a * 4 + r] = *(const f32x4*)(stp + a * 1024 + (i0 + r) * 32 + j0);
  LGK();   // F4: RAW for BS reads

  // ---- Phase 5: read BS<-sb1; gS = MY*St; EMA consume (Mt NT stores); write gS->sb2 ----
  {
    s16x8 BSh[2], BSl[2];
#pragma unroll
    for (int s = 0; s < 2; ++s)
      read_frag_lds(sb1, (16 * s + l15) * 36 + 8 * l4, BSh[s], BSl[s]);
    f32x4 gS[2][2];
#pragma unroll
    for (int ms = 0; ms < 2; ++ms)
#pragma unroll
      for (int ns = 0; ns < 2; ++ns) {
        f32x4 acc = {0.f, 0.f, 0.f, 0.f};
        acc = MFMA_B16(Ml[2][ms], BSh[ns], acc);
        acc = MFMA_B16(Mh[2][ms], BSl[ns], acc);
        acc = MFMA_B16(Mh[2][ms], BSh[ns], acc);
        gS[ms][ns] = acc;
      }
    float* outMt = out + OT_ELEMS + (size_t)batch * 5120;
#pragma unroll
    for (int a = 0; a < 5; ++a) {
      const float al = alpha[a], om = 1.0f - al;
#pragma unroll
      for (int r = 0; r < 4; ++r) {
        f32x4 w = om * raw2[a * 4 + r] + al * ph4[r];
        __builtin_nontemporal_store(w, (f32x4*)(outMt + a * 1024 + (i0 + r) * 32 + j0));
      }
    }
#pragma unroll
    for (int ms = 0; ms < 2; ++ms)
#pragma unroll
      for (int ns = 0; ns < 2; ++ns)
#pragma unroll
        for (int r = 0; r < 4; ++r)
          sb2[(16 * ms + 4 * l4 + r) * 36 + 16 * ns + l15] = gS[ms][ns][r];
  }
  LGK();   // F5: RAW for AS reads

  // ---- Phase 6: read AS<-sb2; Ot = gS*MY^T; write o->sb3 ----
  {
    s16x8 ASh[2], ASl[2];
#pragma unroll
    for (int s = 0; s < 2; ++s)
      read_frag_lds(sb2, (16 * s + l15) * 36 + 8 * l4, ASh[s], ASl[s]);
    f32x4 o[2][2];
#pragma unroll
    for (int ms = 0; ms < 2; ++ms)
#pragma unroll
      for (int ns = 0; ns < 2; ++ns) {
        f32x4 acc = {0.f, 0.f, 0.f, 0.f};
        acc = MFMA_B16(ASl[ms], Mh[2][ns], acc);
        acc = MFMA_B16(ASh[ms], Ml[2][ns], acc);
        acc = MFMA_B16(ASh[ms], Mh[2][ns], acc);
        o[ms][ns] = acc;
      }
#pragma unroll
    for (int ms = 0; ms < 2; ++ms)
#pragma unroll
      for (int ns = 0; ns < 2; ++ns)
#pragma unroll
        for (int r = 0; r < 4; ++r)
          sb3[(16 * ms + 4 * l4 + r) * 36 + 16 * ns + l15] = o[ms][ns][r];
  }
  LGK();   // F6: RAW for Ot rowtile read

  // ---- Phase 7: read Ot<-sb3 rowtile; NT store ----
  float* outOt = out + (size_t)batch * 1024;
#pragma unroll
  for (int r = 0; r < 4; ++r) {
    f32x4 ov = *(const f32x4*)(sb3 + (i0 + r) * 36 + j0);
    __builtin_nontemporal_store(ov, (f32x4*)(outOt + (i0 + r) * 32 + j0));
  }
}

extern "C" void kernel_launch(void* const* d_in, const int* in_sizes, int n_in,
                              void* d_out, int out_size, void* d_ws, size_t ws_size,
                              hipStream_t stream) {
  const float* X     = (const float*)d_in[0];
  const float* state = (const float*)d_in[1];
  const float* WR    = (const float*)d_in[2];
  const float* Wt    = (const float*)d_in[3];
  const float* Wphi  = (const float*)d_in[4];
  const float* Ws    = (const float*)d_in[5];
  const float* Br    = (const float*)d_in[6];
  const float* Bt    = (const float*)d_in[7];
  const float* By    = (const float*)d_in[8];
  float* m_ws = (float*)d_ws;   // 4*1024 floats: MR, MT, MY, P (row-major)
  float* outp = (float*)d_out;

  cayley_kernel<<<3, 1024, 0, stream>>>(Br, Bt, By, m_ws);
  combine_kernel<<<1, 1024, 0, stream>>>(m_ws);
  spdsru_main<<<NB, 64, 0, stream>>>(X, state, WR, Wt, Wphi, Ws, m_ws, outp);
}